// Round 7
// baseline (169.969 us; speedup 1.0000x reference)
//
#include <hip/hip_runtime.h>

#define IMG_W 512
#define IMG_H 512
#define BATCH 64
#define SLAB_ROWS 32
#define SLABS (IMG_H / SLAB_ROWS)      // 16
#define NBLOCKS (BATCH * SLABS)        // 1024 blocks x 256 threads
#define NPIX (BATCH * IMG_W * IMG_H)
#define NSUMS (NBLOCKS * 4)            // one partial per wave

// One chunk buffer: 10 input rows x 2 images x 512 floats = 40,960 B.
// Two buffers = 81,920 B LDS -> exactly 2 blocks/CU. No padding (DMA needs
// contiguous 1KB wave-writes); b128 row reads don't care about row stride.
#define BUF_FLOATS (10 * 2 * 512)
#define IMG_OFF (10 * 512)

__device__ __forceinline__ float fast_sqrtf(float x) {
    return __builtin_amdgcn_sqrtf(x);
}

// Async-stage 10 rows x 2 images (gy0..gy0+9) into LDS buffer `base`.
// 40 wave-instructions of 1KB each, round-robined over the 4 waves.
// Zero VGPR cost -> the compiler cannot sink/serialize the prefetch
// (R4-R6 lesson: register prefetch gets flattened by the allocator).
__device__ __forceinline__ void stage(float* base, const float* gp,
                                      const float* gt, int gy0,
                                      int lane, int w) {
    for (int k = w; k < 40; k += 4) {          // wave-uniform control
        int img  = (k >= 20) ? 1 : 0;
        int rem  = k - img * 20;
        int row  = rem >> 1;
        int half = rem & 1;
        int gy   = gy0 + row;
        int fi   = img * IMG_OFF + row * 512 + (half << 8);  // + lane*4 by HW
        if ((unsigned)gy < (unsigned)IMG_H) {
            const float* g = (img ? gt : gp) +
                             ((size_t)gy << 9) + (half << 8) + (lane << 2);
            __builtin_amdgcn_global_load_lds(
                (const __attribute__((address_space(1))) void*)g,
                (__attribute__((address_space(3))) void*)(base + fi),
                16, 0, 0);
        } else {
            // 'SAME' zero padding rows (slab 0 top, slab 15 bottom)
            float4 z = {0.f, 0.f, 0.f, 0.f};
            *(float4*)(base + fi + (lane << 2)) = z;
        }
    }
}

// 10-wide window of one LDS row; image edges -> 0 ('SAME' padding).
__device__ __forceinline__ void win10(const float* rp, int tx, float* h) {
    const int x0 = tx << 3;
    float4 a = *(const float4*)(rp + x0);
    float4 b = *(const float4*)(rp + x0 + 4);
    h[0] = (tx == 0) ? 0.f : rp[x0 - 1];
    h[1] = a.x; h[2] = a.y; h[3] = a.z; h[4] = a.w;
    h[5] = b.x; h[6] = b.y; h[7] = b.z; h[8] = b.w;
    h[9] = (tx == 63) ? 0.f : rp[x0 + 8];
}

// Sobel magnitudes for this thread's 2 output rows x 8 cols from one image
// region (10 rows x 512 floats). All register arrays constant-indexed after
// inlining (R3 spill lesson).
__device__ __forceinline__ void sobel8x2(const float* img, int w, int tx,
                                         float mag[2][8]) {
    float h0[10], h1[10], h2[10], h3[10];
    win10(img + (2 * w    ) * 512, tx, h0);
    win10(img + (2 * w + 1) * 512, tx, h1);
    win10(img + (2 * w + 2) * 512, tx, h2);
    win10(img + (2 * w + 3) * 512, tx, h3);
    float c0[10], c1[10];
#pragma unroll
    for (int j = 0; j < 10; ++j) {
        c0[j] = fmaf(2.f, h1[j], h0[j]) + h2[j];
        c1[j] = fmaf(2.f, h2[j], h1[j]) + h3[j];
    }
#pragma unroll
    for (int j = 0; j < 8; ++j) {
        float t0 = fmaf(2.f, h2[j + 1], h2[j]) + h2[j + 2];
        float b0 = fmaf(2.f, h0[j + 1], h0[j]) + h0[j + 2];
        float gh0 = t0 - b0;
        float gv0 = c0[j + 2] - c0[j];
        mag[0][j] = fast_sqrtf(fmaf(gv0, gv0, fmaf(gh0, gh0, 1e-18f)));
        float t1 = fmaf(2.f, h3[j + 1], h3[j]) + h3[j + 2];
        float b1 = fmaf(2.f, h1[j + 1], h1[j]) + h1[j + 2];
        float gh1 = t1 - b1;
        float gv1 = c1[j + 2] - c1[j];
        mag[1][j] = fast_sqrtf(fmaf(gv1, gv1, fmaf(gh1, gh1, 1e-18f)));
    }
}

__device__ __forceinline__ void compute_chunk(const float* buf, int w, int tx,
                                              float& lsum) {
    float mp[2][8], mt[2][8];
    sobel8x2(buf, w, tx, mp);
    sobel8x2(buf + IMG_OFF, w, tx, mt);
#pragma unroll
    for (int o = 0; o < 2; ++o)
#pragma unroll
        for (int j = 0; j < 8; ++j)
            lsum += fabsf(mt[o][j] - mp[o][j]); // == sqrt(d^2+eps)*(d^2!=0)
}

__global__ __launch_bounds__(256) void sobel_loss_kernel(
    const float* __restrict__ yp, const float* __restrict__ yt,
    float* __restrict__ wsums)
{
    __shared__ __align__(16) float lds[2 * BUF_FLOATS];
    float* bufA = lds;
    float* bufB = lds + BUF_FLOATS;

    const int tid  = threadIdx.x;
    const int lane = tid & 63;
    const int tx   = lane;               // x-strip: cols tx*8 .. tx*8+7
    const int w    = tid >> 6;           // wave id: output rows 2w,2w+1 of chunk
    const int bid  = blockIdx.x;
    const int b    = bid >> 4;           // image (16 slabs/image)
    const int slab = bid & (SLABS - 1);
    const int y0   = slab * SLAB_ROWS;

    const float* imgp = yp + (size_t)b * (IMG_W * IMG_H);
    const float* imgt = yt + (size_t)b * (IMG_W * IMG_H);

    float lsum = 0.f;

    // Chunk c computes output rows y0+8c..y0+8c+7 from input rows
    // y0+8c-1..y0+8c+8 (self-contained 10-row buffer; 2-row halo refetched
    // per chunk, L2/L3-hot).
    stage(bufA, imgp, imgt, y0 - 1, lane, w);   // c0
    __syncthreads();                             // startup drain
    stage(bufB, imgp, imgt, y0 + 7, lane, w);   // prefetch c1
    compute_chunk(bufA, w, tx, lsum);            // c0
    __syncthreads();                             // drain c1 (overlapped)
    stage(bufA, imgp, imgt, y0 + 15, lane, w);  // prefetch c2
    compute_chunk(bufB, w, tx, lsum);            // c1
    __syncthreads();
    stage(bufB, imgp, imgt, y0 + 23, lane, w);  // prefetch c3
    compute_chunk(bufA, w, tx, lsum);            // c2
    __syncthreads();
    compute_chunk(bufB, w, tx, lsum);            // c3

    // Per-wave reduction; one partial per wave (no extra LDS/barrier).
#pragma unroll
    for (int off = 32; off > 0; off >>= 1)
        lsum += __shfl_down(lsum, off, 64);
    if (lane == 0)
        wsums[bid * 4 + w] = lsum;
}

__global__ __launch_bounds__(256) void reduce_final(
    const float* __restrict__ wsums, float* __restrict__ out)
{
    __shared__ float wred[4];
    const int tid = threadIdx.x;
    float s = 0.f;
    for (int i = tid; i < NSUMS; i += 256) s += wsums[i];
#pragma unroll
    for (int off = 32; off > 0; off >>= 1)
        s += __shfl_down(s, off, 64);
    if ((tid & 63) == 0) wred[tid >> 6] = s;
    __syncthreads();
    if (tid == 0)
        out[0] = (wred[0] + wred[1] + wred[2] + wred[3]) * (1.0f / (float)NPIX);
}

extern "C" void kernel_launch(void* const* d_in, const int* in_sizes, int n_in,
                              void* d_out, int out_size, void* d_ws, size_t ws_size,
                              hipStream_t stream) {
    const float* yp = (const float*)d_in[0];
    const float* yt = (const float*)d_in[1];
    float* out = (float*)d_out;

    float* wsums = (float*)d_ws;   // 16 KB of workspace
    sobel_loss_kernel<<<NBLOCKS, 256, 0, stream>>>(yp, yt, wsums);
    reduce_final<<<1, 256, 0, stream>>>(wsums, out);
}

// Round 8
// 144.641 us; speedup vs baseline: 1.1751x; 1.1751x over previous
//
#include <hip/hip_runtime.h>

#define IMG_W 512
#define IMG_H 512
#define BATCH 64
#define SLAB_ROWS 16
#define SLABS (IMG_H / SLAB_ROWS)   // 32 slabs/image
#define NBLOCKS (BATCH * SLABS)     // 2048 blocks x 256 threads
#define NPIX (BATCH * IMG_W * IMG_H)

__device__ __forceinline__ float fast_sqrtf(float x) {
    return __builtin_amdgcn_sqrtf(x);
}

// R7 design: one self-contained task per thread (4 out rows x 8 cols from
// 6 input rows x 2 images = 24 float4 loads). All loads are needed before
// any compute, so the allocator cannot sink them (R6 lesson: sunk loads ->
// 4KB/wave in flight -> latency-bound at 2.2 TB/s). One vmcnt wait per
// image, ~24KB/wave in flight. All indices compile-time (R3 spill lesson).

// 10-wide window from two float4 + shfl halo (image x-edges -> 0).
#define MKWIN(W, A, B)                                                         \
    float W[10];                                                               \
    {                                                                          \
        float l_ = __shfl_up((B).w, 1, 64);                                    \
        float r_ = __shfl_down((A).x, 1, 64);                                  \
        W[0] = (lane == 0) ? 0.f : l_;                                         \
        W[1] = (A).x; W[2] = (A).y; W[3] = (A).z; W[4] = (A).w;                \
        W[5] = (B).x; W[6] = (B).y; W[7] = (B).z; W[8] = (B).w;                \
        W[9] = (lane == 63) ? 0.f : r_;                                        \
    }

// horizontal 1-2-1 sums of one row (8 wide)
#define MKHS(HS, W)                                                            \
    float HS[8];                                                               \
    _Pragma("unroll")                                                          \
    for (int j = 0; j < 8; ++j)                                                \
        HS[j] = fmaf(2.f, W[j + 1], W[j]) + W[j + 2];

// one output row O: rows WA(y-1), WB(y), WC(y+1)
#define DO_OUT(O, WA, WB, WC, HSA, HSC, MAG)                                   \
    {                                                                          \
        float c_[10];                                                          \
        _Pragma("unroll")                                                      \
        for (int k = 0; k < 10; ++k)                                           \
            c_[k] = fmaf(2.f, WB[k], WA[k]) + WC[k];                           \
        _Pragma("unroll")                                                      \
        for (int j = 0; j < 8; ++j) {                                          \
            float gh = HSC[j] - HSA[j];                                        \
            float gv = c_[j + 2] - c_[j];                                      \
            MAG[O][j] = fast_sqrtf(fmaf(gv, gv, fmaf(gh, gh, 1e-18f)));        \
        }                                                                      \
    }

// Sobel magnitudes, 4 output rows x 8 cols, from 6 rows (12 float4).
#define SOBEL_IMG(MAG, A0, B0, A1, B1, A2, B2, A3, B3, A4, B4, A5, B5)         \
    {                                                                          \
        MKWIN(w0_, A0, B0) MKWIN(w1_, A1, B1) MKWIN(w2_, A2, B2)               \
        MKWIN(w3_, A3, B3) MKWIN(w4_, A4, B4) MKWIN(w5_, A5, B5)               \
        MKHS(h0_, w0_) MKHS(h1_, w1_) MKHS(h2_, w2_)                           \
        MKHS(h3_, w3_) MKHS(h4_, w4_) MKHS(h5_, w5_)                           \
        DO_OUT(0, w0_, w1_, w2_, h0_, h2_, MAG)                                \
        DO_OUT(1, w1_, w2_, w3_, h1_, h3_, MAG)                                \
        DO_OUT(2, w2_, w3_, w4_, h2_, h4_, MAG)                                \
        DO_OUT(3, w3_, w4_, w5_, h3_, h5_, MAG)                                \
    }

// Load input row ty-1+I (y clamped; OOB rows zeroed after, wave-uniformly).
#define LOADR(I, A, B, IMG)                                                    \
    float4 A, B;                                                               \
    {                                                                          \
        int yy = ty - 1 + (I);                                                 \
        int yc = yy < 0 ? 0 : (yy > IMG_H - 1 ? IMG_H - 1 : yy);               \
        const float* r_ = (IMG) + ((size_t)yc << 9) + x0;                      \
        A = *(const float4*)r_;                                                \
        B = *(const float4*)(r_ + 4);                                          \
    }

__global__ __launch_bounds__(256) void sobel_loss_kernel(
    const float* __restrict__ yp, const float* __restrict__ yt,
    float* __restrict__ bsums)
{
    __shared__ float wred[4];

    const int tid  = threadIdx.x;
    const int lane = tid & 63;
    const int bid  = blockIdx.x;
    const int b    = bid >> 5;                      // image (32 slabs/image)
    const int slab = bid & (SLABS - 1);
    const int ty   = slab * SLAB_ROWS + ((tid >> 6) << 2);  // wave-uniform
    const int x0   = lane << 3;                     // cols x0..x0+7

    const float* imgp = yp + ((size_t)b << 18);
    const float* imgt = yt + ((size_t)b << 18);

    // ---- Issue all 24 loads back-to-back (24 KB/wave in flight) ----
    LOADR(0, A0p, B0p, imgp) LOADR(1, A1p, B1p, imgp) LOADR(2, A2p, B2p, imgp)
    LOADR(3, A3p, B3p, imgp) LOADR(4, A4p, B4p, imgp) LOADR(5, A5p, B5p, imgp)
    LOADR(0, A0t, B0t, imgt) LOADR(1, A1t, B1t, imgt) LOADR(2, A2t, B2t, imgt)
    LOADR(3, A3t, B3t, imgt) LOADR(4, A4t, B4t, imgt) LOADR(5, A5t, B5t, imgt)

    // 'SAME' zero padding for y-edge rows (wave-uniform branches)
    const float4 z4 = {0.f, 0.f, 0.f, 0.f};
    if (ty == 0)            { A0p = z4; B0p = z4; A0t = z4; B0t = z4; }
    if (ty + 4 == IMG_H)    { A5p = z4; B5p = z4; A5t = z4; B5t = z4; }

    // ---- Compute (p first: its wait leaves t's loads outstanding) ----
    float magp[4][8], magt[4][8];
    SOBEL_IMG(magp, A0p, B0p, A1p, B1p, A2p, B2p, A3p, B3p, A4p, B4p, A5p, B5p)
    SOBEL_IMG(magt, A0t, B0t, A1t, B1t, A2t, B2t, A3t, B3t, A4t, B4t, A5t, B5t)

    float lsum = 0.f;
#pragma unroll
    for (int o = 0; o < 4; ++o)
#pragma unroll
        for (int j = 0; j < 8; ++j)
            lsum += fabsf(magt[o][j] - magp[o][j]); // == sqrt(d^2+eps)*(d^2!=0)

    // ---- Block reduction ----
#pragma unroll
    for (int off = 32; off > 0; off >>= 1)
        lsum += __shfl_down(lsum, off, 64);
    if (lane == 0) wred[tid >> 6] = lsum;
    __syncthreads();
    if (tid == 0)
        bsums[bid] = wred[0] + wred[1] + wred[2] + wred[3];
}

__global__ __launch_bounds__(256) void reduce_final(
    const float* __restrict__ bsums, float* __restrict__ out)
{
    __shared__ float wred[4];
    const int tid = threadIdx.x;
    float s = 0.f;
    for (int i = tid; i < NBLOCKS; i += 256) s += bsums[i];
#pragma unroll
    for (int off = 32; off > 0; off >>= 1)
        s += __shfl_down(s, off, 64);
    if ((tid & 63) == 0) wred[tid >> 6] = s;
    __syncthreads();
    if (tid == 0)
        out[0] = (wred[0] + wred[1] + wred[2] + wred[3]) * (1.0f / (float)NPIX);
}

extern "C" void kernel_launch(void* const* d_in, const int* in_sizes, int n_in,
                              void* d_out, int out_size, void* d_ws, size_t ws_size,
                              hipStream_t stream) {
    const float* yp = (const float*)d_in[0];
    const float* yt = (const float*)d_in[1];
    float* out = (float*)d_out;

    float* bsums = (float*)d_ws;   // 8 KB of workspace
    sobel_loss_kernel<<<NBLOCKS, 256, 0, stream>>>(yp, yt, bsums);
    reduce_final<<<1, 256, 0, stream>>>(bsums, out);
}

// Round 9
// 142.615 us; speedup vs baseline: 1.1918x; 1.0142x over previous
//
#include <hip/hip_runtime.h>

#define IMG_W 512
#define IMG_H 512
#define BATCH 64
#define SLAB_ROWS 16
#define SLABS (IMG_H / SLAB_ROWS)   // 32 slabs/image
#define NBLOCKS (BATCH * SLABS)     // 2048 blocks x 256 threads
#define NPIX (BATCH * IMG_W * IMG_H)

typedef float f32x4 __attribute__((ext_vector_type(4)));

__device__ __forceinline__ float fast_sqrtf(float x) {
    return __builtin_amdgcn_sqrtf(x);
}

// R8 lesson: VGPR=76 proved the compiler re-sank the 24-load batch into
// {load,wait,compute} chains (~12 exposed latencies/wave -> the 44us
// plateau; model matches VALUBusy=24%). R9: loads are asm volatile
// (unsinkable, strict order), with exactly TWO explicit s_waitcnt per wave:
// vmcnt(12) before p-compute (t's 12KB stays in flight), vmcnt(0) before
// t-compute. The waitcnt asms carry tied +v operands so no use can be
// scheduled before them. Compiler inserts no waits of its own (it tracks
// no VMEM). All indices compile-time (R3 spill lesson).

#define GLOAD(dst, ptr)                                                        \
    asm volatile("global_load_dwordx4 %0, %1, off" : "=v"(dst) : "v"(ptr))

// Load input row ty-1+I (y clamped so the address is always valid;
// y-edge rows are overwritten with zeros after the wait, wave-uniformly).
#define LOADR(I, A, B, IMG)                                                    \
    {                                                                          \
        int yy = ty - 1 + (I);                                                 \
        int yc = yy < 0 ? 0 : (yy > IMG_H - 1 ? IMG_H - 1 : yy);               \
        const float* r_ = (IMG) + ((size_t)yc << 9) + x0;                      \
        GLOAD(A, r_);                                                          \
        GLOAD(B, r_ + 4);                                                      \
    }

// 10-wide window from two f32x4 + shfl halo (image x-edges -> 0).
#define MKWIN(W, A, B)                                                         \
    float W[10];                                                               \
    {                                                                          \
        float l_ = __shfl_up((B)[3], 1, 64);                                   \
        float r_ = __shfl_down((A)[0], 1, 64);                                 \
        W[0] = (lane == 0) ? 0.f : l_;                                         \
        W[1] = (A)[0]; W[2] = (A)[1]; W[3] = (A)[2]; W[4] = (A)[3];            \
        W[5] = (B)[0]; W[6] = (B)[1]; W[7] = (B)[2]; W[8] = (B)[3];            \
        W[9] = (lane == 63) ? 0.f : r_;                                        \
    }

// horizontal 1-2-1 sums of one row (8 wide)
#define MKHS(HS, W)                                                            \
    float HS[8];                                                               \
    _Pragma("unroll")                                                          \
    for (int j = 0; j < 8; ++j)                                                \
        HS[j] = fmaf(2.f, W[j + 1], W[j]) + W[j + 2];

// output row O of image p: store magnitudes
#define DO_OUT_P(O, WA, WB, WC, HSA, HSC)                                      \
    {                                                                          \
        float c_[10];                                                          \
        _Pragma("unroll")                                                      \
        for (int k = 0; k < 10; ++k)                                           \
            c_[k] = fmaf(2.f, WB[k], WA[k]) + WC[k];                           \
        _Pragma("unroll")                                                      \
        for (int j = 0; j < 8; ++j) {                                          \
            float gh = HSC[j] - HSA[j];                                        \
            float gv = c_[j + 2] - c_[j];                                      \
            magp[O][j] = fast_sqrtf(fmaf(gv, gv, fmaf(gh, gh, 1e-18f)));       \
        }                                                                      \
    }

// output row O of image t: fuse |magt - magp| accumulation (no magt array)
#define DO_OUT_T(O, WA, WB, WC, HSA, HSC)                                      \
    {                                                                          \
        float c_[10];                                                          \
        _Pragma("unroll")                                                      \
        for (int k = 0; k < 10; ++k)                                           \
            c_[k] = fmaf(2.f, WB[k], WA[k]) + WC[k];                           \
        _Pragma("unroll")                                                      \
        for (int j = 0; j < 8; ++j) {                                          \
            float gh = HSC[j] - HSA[j];                                        \
            float gv = c_[j + 2] - c_[j];                                      \
            float mt = fast_sqrtf(fmaf(gv, gv, fmaf(gh, gh, 1e-18f)));         \
            lsum += fabsf(mt - magp[O][j]); /* == sqrt(d^2+eps)*(d^2!=0) */    \
        }                                                                      \
    }

#define SOBEL_P(A0, B0, A1, B1, A2, B2, A3, B3, A4, B4, A5, B5)                \
    {                                                                          \
        MKWIN(w0_, A0, B0) MKWIN(w1_, A1, B1) MKWIN(w2_, A2, B2)               \
        MKWIN(w3_, A3, B3) MKWIN(w4_, A4, B4) MKWIN(w5_, A5, B5)               \
        MKHS(h0_, w0_) MKHS(h1_, w1_) MKHS(h2_, w2_)                           \
        MKHS(h3_, w3_) MKHS(h4_, w4_) MKHS(h5_, w5_)                           \
        DO_OUT_P(0, w0_, w1_, w2_, h0_, h2_)                                   \
        DO_OUT_P(1, w1_, w2_, w3_, h1_, h3_)                                   \
        DO_OUT_P(2, w2_, w3_, w4_, h2_, h4_)                                   \
        DO_OUT_P(3, w3_, w4_, w5_, h3_, h5_)                                   \
    }

#define SOBEL_T(A0, B0, A1, B1, A2, B2, A3, B3, A4, B4, A5, B5)                \
    {                                                                          \
        MKWIN(w0_, A0, B0) MKWIN(w1_, A1, B1) MKWIN(w2_, A2, B2)               \
        MKWIN(w3_, A3, B3) MKWIN(w4_, A4, B4) MKWIN(w5_, A5, B5)               \
        MKHS(h0_, w0_) MKHS(h1_, w1_) MKHS(h2_, w2_)                           \
        MKHS(h3_, w3_) MKHS(h4_, w4_) MKHS(h5_, w5_)                           \
        DO_OUT_T(0, w0_, w1_, w2_, h0_, h2_)                                   \
        DO_OUT_T(1, w1_, w2_, w3_, h1_, h3_)                                   \
        DO_OUT_T(2, w2_, w3_, w4_, h2_, h4_)                                   \
        DO_OUT_T(3, w3_, w4_, w5_, h3_, h5_)                                   \
    }

__global__ __launch_bounds__(256) void sobel_loss_kernel(
    const float* __restrict__ yp, const float* __restrict__ yt,
    float* __restrict__ bsums)
{
    __shared__ float wred[4];

    const int tid  = threadIdx.x;
    const int lane = tid & 63;
    const int bid  = blockIdx.x;
    const int b    = bid >> 5;                      // image (32 slabs/image)
    const int slab = bid & (SLABS - 1);
    const int ty   = slab * SLAB_ROWS + ((tid >> 6) << 2);  // wave-uniform
    const int x0   = lane << 3;                     // cols x0..x0+7

    const float* imgp = yp + ((size_t)b << 18);
    const float* imgt = yt + ((size_t)b << 18);

    f32x4 A0p, B0p, A1p, B1p, A2p, B2p, A3p, B3p, A4p, B4p, A5p, B5p;
    f32x4 A0t, B0t, A1t, B1t, A2t, B2t, A3t, B3t, A4t, B4t, A5t, B5t;

    // ---- Issue all 24 loads back-to-back (asm volatile: unsinkable) ----
    LOADR(0, A0p, B0p, imgp) LOADR(1, A1p, B1p, imgp) LOADR(2, A2p, B2p, imgp)
    LOADR(3, A3p, B3p, imgp) LOADR(4, A4p, B4p, imgp) LOADR(5, A5p, B5p, imgp)
    LOADR(0, A0t, B0t, imgt) LOADR(1, A1t, B1t, imgt) LOADR(2, A2t, B2t, imgt)
    LOADR(3, A3t, B3t, imgt) LOADR(4, A4t, B4t, imgt) LOADR(5, A5t, B5t, imgt)

    // ---- Wait for the 12 p-loads only (t's 12KB stays in flight) ----
    asm volatile("s_waitcnt vmcnt(12)"
                 : "+v"(A0p), "+v"(B0p), "+v"(A1p), "+v"(B1p),
                   "+v"(A2p), "+v"(B2p), "+v"(A3p), "+v"(B3p),
                   "+v"(A4p), "+v"(B4p), "+v"(A5p), "+v"(B5p));

    const f32x4 z4 = {0.f, 0.f, 0.f, 0.f};
    if (ty == 0)         { A0p = z4; B0p = z4; }   // 'SAME' zero pad (y)
    if (ty + 4 == IMG_H) { A5p = z4; B5p = z4; }

    float magp[4][8];
    float lsum = 0.f;
    SOBEL_P(A0p, B0p, A1p, B1p, A2p, B2p, A3p, B3p, A4p, B4p, A5p, B5p)

    // ---- Wait for the t-loads, compute fused difference ----
    asm volatile("s_waitcnt vmcnt(0)"
                 : "+v"(A0t), "+v"(B0t), "+v"(A1t), "+v"(B1t),
                   "+v"(A2t), "+v"(B2t), "+v"(A3t), "+v"(B3t),
                   "+v"(A4t), "+v"(B4t), "+v"(A5t), "+v"(B5t));

    if (ty == 0)         { A0t = z4; B0t = z4; }
    if (ty + 4 == IMG_H) { A5t = z4; B5t = z4; }

    SOBEL_T(A0t, B0t, A1t, B1t, A2t, B2t, A3t, B3t, A4t, B4t, A5t, B5t)

    // ---- Block reduction ----
#pragma unroll
    for (int off = 32; off > 0; off >>= 1)
        lsum += __shfl_down(lsum, off, 64);
    if (lane == 0) wred[tid >> 6] = lsum;
    __syncthreads();
    if (tid == 0)
        bsums[bid] = wred[0] + wred[1] + wred[2] + wred[3];
}

__global__ __launch_bounds__(256) void reduce_final(
    const float* __restrict__ bsums, float* __restrict__ out)
{
    __shared__ float wred[4];
    const int tid = threadIdx.x;
    float s = 0.f;
    for (int i = tid; i < NBLOCKS; i += 256) s += bsums[i];
#pragma unroll
    for (int off = 32; off > 0; off >>= 1)
        s += __shfl_down(s, off, 64);
    if ((tid & 63) == 0) wred[tid >> 6] = s;
    __syncthreads();
    if (tid == 0)
        out[0] = (wred[0] + wred[1] + wred[2] + wred[3]) * (1.0f / (float)NPIX);
}

extern "C" void kernel_launch(void* const* d_in, const int* in_sizes, int n_in,
                              void* d_out, int out_size, void* d_ws, size_t ws_size,
                              hipStream_t stream) {
    const float* yp = (const float*)d_in[0];
    const float* yt = (const float*)d_in[1];
    float* out = (float*)d_out;

    float* bsums = (float*)d_ws;   // 8 KB of workspace
    sobel_loss_kernel<<<NBLOCKS, 256, 0, stream>>>(yp, yt, bsums);
    reduce_final<<<1, 256, 0, stream>>>(bsums, out);
}